// Round 1
// 198.219 us; speedup vs baseline: 1.0268x; 1.0268x over previous
//
#include <hip/hip_runtime.h>

#define N_CHROM 23
#define BINS_PER_CHROM 5000
#define BSZ 16
#define SSZ 512
#define EOS_DIM 512
#define BIN_DIM 256
#define D_MODEL 512
#define VOCAB (N_CHROM * BINS_PER_CHROM)   // 115000
#define ROWS (N_CHROM * BSZ * SSZ)         // 188416
#define PRED_SIZE (ROWS * 3)               // 565248
#define NCB (N_CHROM * BSZ)                // 368

// Workspace layout (floats):
//   [0,768)        M[3][256]
//   [768,2304)     Meos[3][512]
//   [2304,2308)    cst[3]  (b_fc[w] + sum_e W_fc[w][512+e]*b_eos[e])
//   [2432,3904)    E[368][4]  (per-(c,b) eos scalar, .w unused; 16B aligned)
//   [4096,...)     pt[VOCAB] as float4 (x,y,z = projected logits)
#define WS_M     0
#define WS_MEOS  768
#define WS_CONST 2304
#define WS_E     2432
#define WS_PT    4096

typedef float fvec4 __attribute__((ext_vector_type(4)));

// ---------------------------------------------------------------------------
// Kernel 1: M[n][e]    = sum_d W_fc[n][d]     * W_bin[d][e]   (e<256)
//           Meos[n][e] = sum_d W_fc[n][512+d] * W_eos[d][e]   (e<512)
//           cst[n]     = b_fc[n] + sum_e W_fc[n][512+e] * b_eos[e]
// ---------------------------------------------------------------------------
__global__ __launch_bounds__(256) void precompute_M(
    const float* __restrict__ W_bin, const float* __restrict__ W_eos,
    const float* __restrict__ W_fc, const float* __restrict__ b_eos,
    const float* __restrict__ b_fc, float* __restrict__ ws)
{
    __shared__ float wfc_s[3][512];
    __shared__ float red[3][8][32];
    const int bid = blockIdx.x;
    const bool isM = (bid < 8);
    const float* src = isM ? W_bin : W_eos;
    const int ld   = isM ? 256 : 512;
    const int wofs = isM ? 0 : 512;
    const int eb   = (isM ? bid : (bid - 8)) * 32;
    float* dst = ws + (isM ? WS_M : WS_MEOS);

    const int t = threadIdx.x;
    for (int i = t; i < 3 * 512; i += 256) {
        int n = i >> 9, d = i & 511;
        wfc_s[n][d] = W_fc[n * 1024 + wofs + d];
    }
    __syncthreads();

    const int el = t & 31, slice = t >> 5;
    const int e = eb + el;
    float a0 = 0.f, a1 = 0.f, a2 = 0.f;
    const int d0 = slice * 64;
    for (int dd = 0; dd < 64; ++dd) {
        int d = d0 + dd;
        float v = src[d * ld + e];
        a0 += wfc_s[0][d] * v;
        a1 += wfc_s[1][d] * v;
        a2 += wfc_s[2][d] * v;
    }
    red[0][slice][el] = a0;
    red[1][slice][el] = a1;
    red[2][slice][el] = a2;
    __syncthreads();

    if (slice < 3) {
        float s = 0.f;
        for (int q = 0; q < 8; ++q) s += red[slice][q][el];
        dst[slice * ld + e] = s;
    }

    // fold the row-invariant fc constant once (block 0, waves 0..2)
    if (bid == 0) {
        const int wv = t >> 6, ln = t & 63;
        if (wv < 3) {
            const float* wf2 = W_fc + wv * 1024 + 512;
            float s = 0.f;
#pragma unroll
            for (int e0 = 0; e0 < 512; e0 += 64) s += wf2[e0 + ln] * b_eos[e0 + ln];
            for (int m = 32; m; m >>= 1) s += __shfl_xor(s, m);
            if (ln == 0) ws[WS_CONST + wv] = s + b_fc[wv];
        }
    }
}

// ---------------------------------------------------------------------------
// Kernel 2: blocks [0,368): E[cb][w] = eos[b,c,:]·Meos[w] + cst[w]
//           blocks [368,..): project the embedding table through M.
// Table rows are read ONCE -> nontemporal loads so pt / gather data stay in L2.
// ---------------------------------------------------------------------------
__global__ __launch_bounds__(256) void project_table(
    const float* __restrict__ table, const float* __restrict__ eos_emb,
    float* __restrict__ ws)
{
    const int bid = blockIdx.x;
    if (bid < NCB) {
        const int c = bid >> 4, b = bid & 15;
        const int wv = threadIdx.x >> 6, ln = threadIdx.x & 63;
        if (wv < 3) {
            const float* eos = eos_emb + (b * N_CHROM + c) * EOS_DIM;
            const float* me  = ws + WS_MEOS + wv * 512;
            float s = 0.f;
#pragma unroll
            for (int e0 = 0; e0 < 512; e0 += 64) {
                int e = e0 + ln;
                s += eos[e] * me[e];
            }
            for (int m = 32; m; m >>= 1) s += __shfl_xor(s, m);
            if (ln == 0) ws[WS_E + bid * 4 + wv] = s + ws[WS_CONST + wv];
        }
        return;
    }

    const int wave = threadIdx.x >> 6, lane = threadIdx.x & 63;
    const int rbase = ((bid - NCB) * 4 + wave) * 8;
    if (rbase >= VOCAB) return;

    const fvec4* mm = (const fvec4*)(ws + WS_M);
    const fvec4 m0 = mm[lane];
    const fvec4 m1 = mm[64 + lane];
    const fvec4 m2 = mm[128 + lane];
    fvec4* pt = (fvec4*)(ws + WS_PT);

    const fvec4* tb = (const fvec4*)table;
    fvec4 v[8];
#pragma unroll
    for (int k = 0; k < 8; ++k)
        v[k] = __builtin_nontemporal_load(&tb[(rbase + k) * 64 + lane]);

#pragma unroll
    for (int k = 0; k < 8; ++k) {
        float p0 = v[k].x * m0.x + v[k].y * m0.y + v[k].z * m0.z + v[k].w * m0.w;
        float p1 = v[k].x * m1.x + v[k].y * m1.y + v[k].z * m1.z + v[k].w * m1.w;
        float p2 = v[k].x * m2.x + v[k].y * m2.y + v[k].z * m2.z + v[k].w * m2.w;
        for (int m = 32; m; m >>= 1) {
            p0 += __shfl_xor(p0, m);
            p1 += __shfl_xor(p1, m);
            p2 += __shfl_xor(p2, m);
        }
        if (lane == 0) pt[rbase + k] = (fvec4){p0, p1, p2, 0.f};
    }
}

// ---------------------------------------------------------------------------
// Kernel 3: pure gather + relu + targets passthrough. No LDS, no barrier.
// E row is wave-uniform per block (blockIdx>>1) -> scalar loads.
// ---------------------------------------------------------------------------
__global__ __launch_bounds__(256) void gather_out(
    const int* __restrict__ sampled, const int* __restrict__ targets,
    const float* __restrict__ ws, float* __restrict__ out)
{
    const int r = blockIdx.x * 256 + threadIdx.x;
    const int cb = blockIdx.x >> 1;          // 512 rows per (c,b)
    const int c = cb >> 4;

    const int bin = __builtin_nontemporal_load(&sampled[r]);
    const int tgt = __builtin_nontemporal_load(&targets[r]);

    const fvec4 e = ((const fvec4*)(ws + WS_E))[cb];
    const fvec4 p = ((const fvec4*)(ws + WS_PT))[c * BINS_PER_CHROM + bin];

    const int o = r * 3;
    __builtin_nontemporal_store(fmaxf(p.x + e.x, 0.f), &out[o + 0]);
    __builtin_nontemporal_store(fmaxf(p.y + e.y, 0.f), &out[o + 1]);
    __builtin_nontemporal_store(fmaxf(p.z + e.z, 0.f), &out[o + 2]);
    __builtin_nontemporal_store((float)tgt, &out[PRED_SIZE + r]);
}

extern "C" void kernel_launch(void* const* d_in, const int* in_sizes, int n_in,
                              void* d_out, int out_size, void* d_ws, size_t ws_size,
                              hipStream_t stream) {
    const float* eos_emb = (const float*)d_in[0];
    const int*   sampled = (const int*)d_in[1];
    const int*   targets = (const int*)d_in[2];
    const float* table   = (const float*)d_in[3];
    const float* W_bin   = (const float*)d_in[4];
    const float* W_eos   = (const float*)d_in[5];
    const float* b_eos   = (const float*)d_in[6];
    const float* W_fc    = (const float*)d_in[7];
    const float* b_fc    = (const float*)d_in[8];
    float* out = (float*)d_out;
    float* ws  = (float*)d_ws;

    precompute_M<<<24, 256, 0, stream>>>(W_bin, W_eos, W_fc, b_eos, b_fc, ws);
    // 368 E-blocks + 14375 table waves (4 waves/block -> 3594 blocks)
    project_table<<<NCB + (VOCAB / 8 + 3) / 4, 256, 0, stream>>>(table, eos_emb, ws);
    gather_out<<<ROWS / 256, 256, 0, stream>>>(sampled, targets, ws, out);
}

// Round 2
// 191.327 us; speedup vs baseline: 1.0638x; 1.0360x over previous
//
#include <hip/hip_runtime.h>

#define N_CHROM 23
#define BINS_PER_CHROM 5000
#define BSZ 16
#define SSZ 512
#define EOS_DIM 512
#define BIN_DIM 256
#define D_MODEL 512
#define VOCAB (N_CHROM * BINS_PER_CHROM)   // 115000
#define ROWS (N_CHROM * BSZ * SSZ)         // 188416
#define PRED_SIZE (ROWS * 3)               // 565248
#define NCB (N_CHROM * BSZ)                // 368

// Workspace layout (floats):
//   [0,768)        M[3][256]
//   [768,2304)     Meos[3][512]
//   [2304,2308)    cst[3]  (b_fc[w] + sum_e W_fc[w][512+e]*b_eos[e])
//   [2432,3904)    E[368][4]  (per-(c,b) eos scalar, .w unused; 16B aligned)
//   [4096,...)     pt[VOCAB] as float4 (x,y,z = projected logits)
#define WS_M     0
#define WS_MEOS  768
#define WS_CONST 2304
#define WS_E     2432
#define WS_PT    4096

typedef float fvec4 __attribute__((ext_vector_type(4)));

// ---------------------------------------------------------------------------
// Kernel 1: M[n][e]    = sum_d W_fc[n][d]     * W_bin[d][e]   (e<256)
//           Meos[n][e] = sum_d W_fc[n][512+d] * W_eos[d][e]   (e<512)
//           cst[n]     = b_fc[n] + sum_e W_fc[n][512+e] * b_eos[e]
// ---------------------------------------------------------------------------
__global__ __launch_bounds__(256) void precompute_M(
    const float* __restrict__ W_bin, const float* __restrict__ W_eos,
    const float* __restrict__ W_fc, const float* __restrict__ b_eos,
    const float* __restrict__ b_fc, float* __restrict__ ws)
{
    __shared__ float wfc_s[3][512];
    __shared__ float red[3][8][32];
    const int bid = blockIdx.x;
    const bool isM = (bid < 8);
    const float* src = isM ? W_bin : W_eos;
    const int ld   = isM ? 256 : 512;
    const int wofs = isM ? 0 : 512;
    const int eb   = (isM ? bid : (bid - 8)) * 32;
    float* dst = ws + (isM ? WS_M : WS_MEOS);

    const int t = threadIdx.x;
    for (int i = t; i < 3 * 512; i += 256) {
        int n = i >> 9, d = i & 511;
        wfc_s[n][d] = W_fc[n * 1024 + wofs + d];
    }
    __syncthreads();

    const int el = t & 31, slice = t >> 5;
    const int e = eb + el;
    float a0 = 0.f, a1 = 0.f, a2 = 0.f;
    const int d0 = slice * 64;
    for (int dd = 0; dd < 64; ++dd) {
        int d = d0 + dd;
        float v = src[d * ld + e];
        a0 += wfc_s[0][d] * v;
        a1 += wfc_s[1][d] * v;
        a2 += wfc_s[2][d] * v;
    }
    red[0][slice][el] = a0;
    red[1][slice][el] = a1;
    red[2][slice][el] = a2;
    __syncthreads();

    if (slice < 3) {
        float s = 0.f;
        for (int q = 0; q < 8; ++q) s += red[slice][q][el];
        dst[slice * ld + e] = s;
    }

    // fold the row-invariant fc constant once (block 0, waves 0..2)
    if (bid == 0) {
        const int wv = t >> 6, ln = t & 63;
        if (wv < 3) {
            const float* wf2 = W_fc + wv * 1024 + 512;
            float s = 0.f;
#pragma unroll
            for (int e0 = 0; e0 < 512; e0 += 64) s += wf2[e0 + ln] * b_eos[e0 + ln];
            for (int m = 32; m; m >>= 1) s += __shfl_xor(s, m);
            if (ln == 0) ws[WS_CONST + wv] = s + b_fc[wv];
        }
    }
}

// ---------------------------------------------------------------------------
// Kernel 2: blocks [0,368): E[cb][w] = eos[b,c,:]·Meos[w] + cst[w]
//           blocks [368,..): project the embedding table through M.
// Table rows are read ONCE -> nontemporal loads so pt / gather data stay in L2.
// Reduction uses a value-halving butterfly: 30 cross-lane ops per wave
// (12+6+3 exchange stages + 3x3 final) instead of 8*3*6=144, keeping the
// per-CU LDS pipe off the critical path (HBM-bound at ~800 cyc/wave).
// Final store: one instruction, 8 active lanes (one per 8-lane group/row).
// ---------------------------------------------------------------------------
__global__ __launch_bounds__(256) void project_table(
    const float* __restrict__ table, const float* __restrict__ eos_emb,
    float* __restrict__ ws)
{
    const int bid = blockIdx.x;
    if (bid < NCB) {
        const int c = bid >> 4, b = bid & 15;
        const int wv = threadIdx.x >> 6, ln = threadIdx.x & 63;
        if (wv < 3) {
            const float* eos = eos_emb + (b * N_CHROM + c) * EOS_DIM;
            const float* me  = ws + WS_MEOS + wv * 512;
            float s = 0.f;
#pragma unroll
            for (int e0 = 0; e0 < 512; e0 += 64) {
                int e = e0 + ln;
                s += eos[e] * me[e];
            }
            for (int m = 32; m; m >>= 1) s += __shfl_xor(s, m);
            if (ln == 0) ws[WS_E + bid * 4 + wv] = s + ws[WS_CONST + wv];
        }
        return;
    }

    const int wave = threadIdx.x >> 6, lane = threadIdx.x & 63;
    const int rbase = ((bid - NCB) * 4 + wave) * 8;
    if (rbase >= VOCAB) return;

    const fvec4* mm = (const fvec4*)(ws + WS_M);
    const fvec4 m0 = mm[lane];
    const fvec4 m1 = mm[64 + lane];
    const fvec4 m2 = mm[128 + lane];
    fvec4* pt = (fvec4*)(ws + WS_PT);

    const fvec4* tb = (const fvec4*)table;
    fvec4 v[8];
#pragma unroll
    for (int k = 0; k < 8; ++k)
        v[k] = __builtin_nontemporal_load(&tb[(rbase + k) * 64 + lane]);

    float p[8][3];
#pragma unroll
    for (int k = 0; k < 8; ++k) {
        p[k][0] = v[k].x * m0.x + v[k].y * m0.y + v[k].z * m0.z + v[k].w * m0.w;
        p[k][1] = v[k].x * m1.x + v[k].y * m1.y + v[k].z * m1.z + v[k].w * m1.w;
        p[k][2] = v[k].x * m2.x + v[k].y * m2.y + v[k].z * m2.z + v[k].w * m2.w;
    }

    // Stage 1 (xor 32): halves split rows 0-3 / 4-7. 12 shuffles.
    const bool hi5 = (lane & 32) != 0;
    float q[4][3];
#pragma unroll
    for (int k = 0; k < 4; ++k)
#pragma unroll
        for (int n = 0; n < 3; ++n) {
            float tmp  = hi5 ? p[k][n] : p[k + 4][n];   // send what partner keeps
            float recv = __shfl_xor(tmp, 32);
            q[k][n] = (hi5 ? p[k + 4][n] : p[k][n]) + recv;
        }

    // Stage 2 (xor 16): quarters split local rows {0,1} / {2,3}. 6 shuffles.
    const bool hi4 = (lane & 16) != 0;
    float r[2][3];
#pragma unroll
    for (int k = 0; k < 2; ++k)
#pragma unroll
        for (int n = 0; n < 3; ++n) {
            float tmp  = hi4 ? q[k][n] : q[k + 2][n];
            float recv = __shfl_xor(tmp, 16);
            r[k][n] = (hi4 ? q[k + 2][n] : q[k][n]) + recv;
        }

    // Stage 3 (xor 8): eighths split local rows {0} / {1}. 3 shuffles.
    const bool hi3 = (lane & 8) != 0;
    float s0, s1, s2;
    {
        float t0 = hi3 ? r[0][0] : r[1][0];
        float t1 = hi3 ? r[0][1] : r[1][1];
        float t2 = hi3 ? r[0][2] : r[1][2];
        s0 = (hi3 ? r[1][0] : r[0][0]) + __shfl_xor(t0, 8);
        s1 = (hi3 ? r[1][1] : r[0][1]) + __shfl_xor(t1, 8);
        s2 = (hi3 ? r[1][2] : r[0][2]) + __shfl_xor(t2, 8);
    }

    // Stages 4-6: plain reduce of 3 values over 8-lane group. 9 shuffles.
#pragma unroll
    for (int m = 4; m; m >>= 1) {
        s0 += __shfl_xor(s0, m);
        s1 += __shfl_xor(s1, m);
        s2 += __shfl_xor(s2, m);
    }

    // Group g = lane>>3 owns row (bit5->2, bit4->1, bit3->0) == g.
    if ((lane & 7) == 0)
        pt[rbase + (lane >> 3)] = (fvec4){s0, s1, s2, 0.f};
}

// ---------------------------------------------------------------------------
// Kernel 3: pure gather + relu + targets passthrough. No LDS, no barrier.
// E row is wave-uniform per block (blockIdx>>1) -> scalar loads.
// ---------------------------------------------------------------------------
__global__ __launch_bounds__(256) void gather_out(
    const int* __restrict__ sampled, const int* __restrict__ targets,
    const float* __restrict__ ws, float* __restrict__ out)
{
    const int r = blockIdx.x * 256 + threadIdx.x;
    const int cb = blockIdx.x >> 1;          // 512 rows per (c,b)
    const int c = cb >> 4;

    const int bin = __builtin_nontemporal_load(&sampled[r]);
    const int tgt = __builtin_nontemporal_load(&targets[r]);

    const fvec4 e = ((const fvec4*)(ws + WS_E))[cb];
    const fvec4 p = ((const fvec4*)(ws + WS_PT))[c * BINS_PER_CHROM + bin];

    const int o = r * 3;
    __builtin_nontemporal_store(fmaxf(p.x + e.x, 0.f), &out[o + 0]);
    __builtin_nontemporal_store(fmaxf(p.y + e.y, 0.f), &out[o + 1]);
    __builtin_nontemporal_store(fmaxf(p.z + e.z, 0.f), &out[o + 2]);
    __builtin_nontemporal_store((float)tgt, &out[PRED_SIZE + r]);
}

extern "C" void kernel_launch(void* const* d_in, const int* in_sizes, int n_in,
                              void* d_out, int out_size, void* d_ws, size_t ws_size,
                              hipStream_t stream) {
    const float* eos_emb = (const float*)d_in[0];
    const int*   sampled = (const int*)d_in[1];
    const int*   targets = (const int*)d_in[2];
    const float* table   = (const float*)d_in[3];
    const float* W_bin   = (const float*)d_in[4];
    const float* W_eos   = (const float*)d_in[5];
    const float* b_eos   = (const float*)d_in[6];
    const float* W_fc    = (const float*)d_in[7];
    const float* b_fc    = (const float*)d_in[8];
    float* out = (float*)d_out;
    float* ws  = (float*)d_ws;

    precompute_M<<<24, 256, 0, stream>>>(W_bin, W_eos, W_fc, b_eos, b_fc, ws);
    // 368 E-blocks + 14375 table waves (4 waves/block -> 3594 blocks)
    project_table<<<NCB + (VOCAB / 8 + 3) / 4, 256, 0, stream>>>(table, eos_emb, ws);
    gather_out<<<ROWS / 256, 256, 0, stream>>>(sampled, targets, ws, out);
}